// Round 10
// baseline (250.741 us; speedup 1.0000x reference)
//
#include <hip/hip_runtime.h>
#include <math.h>

#define NVEC 32768   // 32*32*32 vectors
#define NE   1024    // codebook entries
#define ED   64      // embedding dim
#define TOT  2097152 // NVEC*ED total z elements
#define MT   128     // vectors per k_dist block

// d_out offsets (in floats): loss | z_q_st | perplexity | min_encodings | idx
#define O_LOSS   0
#define O_ZQ     1
#define O_PERP   2097153
#define O_MINENC 2097154
#define O_IDX    35651586

// d_ws offsets (in floats)
#define W_PIDX   0        // [32768] final idx (int), written by k_dist
#define W_CS     32768    // [1024] int counts (atomic)
#define W_SUMENC 33792    // [1024*64] float (atomic)
#define W_ESQ    164864   // [1024] ||e||^2, exact np-pairwise

// R23 post-mortem of R22: k_dist pinned at ~90us across SIX variants.
// R21 showed why: chunk barriers phase-lock all 8 waves into the same
// load/FMA phase, so the LDS pipe (~41us) and VALU (~40us) serialize and
// cross-wave overlap is suppressed. R23 structural fix: B STREAMED FROM
// GLOBAL (VMEM/L1 pipe) instead of LDS — each thread's 8 code rows load as
// 8 float4 per c4 with one base + immediate offsets (4 distinct lines/instr,
// 16-lane broadcast, 8KB/wave working set = L1-resident; each block still
// reads emb exactly once = 256KB). This deletes Stage B, s_b, and ALL
// k-loop barriers -> waves free-run, VALU || LDS-A || VMEM-B overlap.
// FMA order (c ascending per (m,k)), esq/zsq rounding, and argmin traversal
// (ch,mu,ku ascending) unchanged -> idx bit-identical. LDS 71KB.

// blocks 0..64: zero cnt+sumenc (66560 floats = 16640 float4) + out[O_LOSS].
// blocks 65..68: esq[code] with the exact np-pairwise rounding.
__global__ void __launch_bounds__(256) k_pre(const float* __restrict__ emb,
                                             float* __restrict__ ws,
                                             float* __restrict__ out) {
    int b = blockIdx.x;
    if (b < 65) {
        int i = b * 256 + threadIdx.x;  // 0..16639, exactly 65*256
        float4 zv; zv.x = 0.f; zv.y = 0.f; zv.z = 0.f; zv.w = 0.f;
        *(float4*)(ws + W_CS + i * 4) = zv;
        if (b == 0 && threadIdx.x == 0) out[O_LOSS] = 0.f;
    } else {
        int code = (b - 65) * 256 + threadIdx.x;  // 4*256 = 1024
        const float* ep = emb + (size_t)code * ED;
        float r[8];
#pragma unroll
        for (int j = 0; j < 8; ++j) r[j] = __fmul_rn(ep[j], ep[j]);
#pragma unroll
        for (int i = 8; i < 64; i += 8)
#pragma unroll
            for (int j = 0; j < 8; ++j)
                r[j] = __fadd_rn(r[j], __fmul_rn(ep[i + j], ep[i + j]));
        ws[W_ESQ + code] = __fadd_rn(
            __fadd_rn(__fadd_rn(r[0], r[1]), __fadd_rn(r[2], r[3])),
            __fadd_rn(__fadd_rn(r[4], r[5]), __fadd_rn(r[6], r[7])));
    }
}

// phys float offset of logical m within an s_a row (perm'd quads)
__device__ __forceinline__ int apos(int m) {
    return ((m & 4) << 4) + ((m >> 3) << 2) + (m & 3);
}

__global__ void __launch_bounds__(512) k_dist(const float* __restrict__ z,
                                              const float* __restrict__ emb,
                                              const float* __restrict__ esq_g,
                                              int* __restrict__ fidx,
                                              int* __restrict__ cnt,
                                              float* __restrict__ sumenc,
                                              float* __restrict__ out) {
    __shared__ __align__(16) float s_a[64 * 128];   // [c][m-perm] 2*z (32 KB)
    __shared__ __align__(16) float s_scr[8448];     // merge/transpose scratch (33 KB)
    __shared__ float s_esq[NE];                     // all 1024 esq (4 KB)
    __shared__ float s_zsq[MT];
    __shared__ int s_bi[MT];

    int tid = threadIdx.x;
    int n0 = blockIdx.x * MT;
    int b = n0 >> 10, hw0 = n0 & 1023;  // MT=128 tile never crosses b
    const float* zb = z + b * 65536 + hw0;

    // Stage A: 64c x 128m = 2048 float4 / 512 thr = 4 each. Perm'd quads.
#pragma unroll
    for (int j = 0; j < 4; ++j) {
        int f4i = j * 512 + tid;
        int q = f4i & 31, c = f4i >> 5;   // c in 0..63
        float4 v = *(const float4*)(zb + (c << 10) + q * 4);
        v.x = __fmul_rn(2.0f, v.x);
        v.y = __fmul_rn(2.0f, v.y);
        v.z = __fmul_rn(2.0f, v.z);
        v.w = __fmul_rn(2.0f, v.w);
        *(float4*)(s_a + c * 128 + ((q & 1) << 6) + ((q >> 1) << 2)) = v;
    }
    // esq: all 1024, coalesced, once
    s_esq[tid] = esq_g[tid];
    s_esq[tid + 512] = esq_g[tid + 512];
    __syncthreads();

    // zsq (threads 0..127): np-pairwise over z; from (2z): exact x0.25.
    if (tid < MT) {
        int p = apos(tid);
        float r[8];
#pragma unroll
        for (int j = 0; j < 8; ++j) {
            float v = s_a[j * 128 + p];
            r[j] = __fmul_rn(v, v);
        }
#pragma unroll
        for (int i = 8; i < 64; i += 8)
#pragma unroll
            for (int j = 0; j < 8; ++j) {
                float v = s_a[(i + j) * 128 + p];
                r[j] = __fadd_rn(r[j], __fmul_rn(v, v));
            }
        s_zsq[tid] = __fmul_rn(0.25f, __fadd_rn(
            __fadd_rn(__fadd_rn(r[0], r[1]), __fadd_rn(r[2], r[3])),
            __fadd_rn(__fadd_rn(r[4], r[5]), __fadd_rn(r[6], r[7]))));
    }
    __syncthreads();

    int mi = tid & 15, ki = tid >> 4;   // 16 m-groups x 32 k-groups
    int kb8 = ki * 8;                   // first code of this thread's 8-row strip
    float zs[8];
#pragma unroll
    for (int mu = 0; mu < 8; ++mu) zs[mu] = s_zsq[8 * mi + mu];

    float bd[8];
    int bix[8];
#pragma unroll
    for (int mu = 0; mu < 8; ++mu) { bd[mu] = 3.4e38f; bix[mu] = kb8; }

    // Main k sweep: 4 strips of 256 codes, NO barriers — waves free-run.
    // B streamed from global: per c4, 8 float4 (one per code row) via one
    // base pointer + immediate offsets (ku*256 + c4*16 bytes <= 2032).
    for (int ch = 0; ch < 4; ++ch) {
        int k0 = ch * 256;
        const float* eb = emb + (size_t)(k0 + kb8) * ED;

        float acc[8][8];
#pragma unroll
        for (int mu = 0; mu < 8; ++mu)
#pragma unroll
            for (int ku = 0; ku < 8; ++ku) acc[mu][ku] = 0.f;

#pragma unroll 4
        for (int c4 = 0; c4 < 16; ++c4) {
            float4 B[8];
#pragma unroll
            for (int ku = 0; ku < 8; ++ku)
                B[ku] = *(const float4*)(eb + ku * ED + c4 * 4);
#pragma unroll
            for (int j = 0; j < 4; ++j) {
                int c = c4 * 4 + j;
                const float* ar = s_a + c * 128 + (mi << 2);
                float4 a0 = *(const float4*)(ar);        // m = 8mi..8mi+3
                float4 a1 = *(const float4*)(ar + 64);   // m = 8mi+4..8mi+7
#pragma unroll
                for (int mu = 0; mu < 8; ++mu) {
                    float a = (mu < 4) ? (&a0.x)[mu] : (&a1.x)[mu - 4];
#pragma unroll
                    for (int ku = 0; ku < 8; ++ku)
                        acc[mu][ku] = __fmaf_rn(a, (&B[ku].x)[j], acc[mu][ku]);
                }
            }
        }

        // d = fl(fl(zsq+esq) - dot2); running argmin (k ascending, as before)
#pragma unroll
        for (int mu = 0; mu < 8; ++mu)
#pragma unroll
            for (int ku = 0; ku < 8; ++ku) {
                float d = __fsub_rn(__fadd_rn(zs[mu], s_esq[k0 + kb8 + ku]),
                                    acc[mu][ku]);
                if (d < bd[mu]) { bd[mu] = d; bix[mu] = k0 + kb8 + ku; }
            }
    }

    // Merge 32 ki candidates per m, lexicographic (d, i) min == np.argmin.
    // s_scr first use here: no prior readers to protect.
    float* red_d = s_scr;               // [32][128] = 4096 floats
    int* red_i = (int*)(s_scr + 4096);  // [32][128]
#pragma unroll
    for (int mu = 0; mu < 8; ++mu) {
        red_d[ki * 128 + 8 * mi + mu] = bd[mu];
        red_i[ki * 128 + 8 * mi + mu] = bix[mu];
    }
    __syncthreads();
    if (tid < MT) {
        float best = red_d[tid];
        int bi = red_i[tid];
#pragma unroll
        for (int q = 1; q < 32; ++q) {
            float d = red_d[q * 128 + tid];
            int i = red_i[q * 128 + tid];
            if (d < best || (d == best && i < bi)) { best = d; bi = i; }
        }
        fidx[n0 + tid] = bi;
        out[O_IDX + n0 + tid] = (float)bi;
        s_bi[tid] = bi;
        atomicAdd(&cnt[bi], 1);  // int atomic: HW, exact
    }
    __syncthreads();  // merge consumed red_*: s_scr free; s_bi visible

    // Transpose 0.5*z into s_scr at stride 65 (m-major), 8320 <= 8448.
    {
        int m = tid & 127, qt = tid >> 7;
        int p = apos(m);
#pragma unroll
        for (int j = 0; j < 16; ++j) {
            int c = qt * 16 + j;
            s_scr[m * 65 + c] = __fmul_rn(0.5f, s_a[c * 128 + p]);
        }
    }
    __syncthreads();

    // Coalesced scatter: wave w handles vectors m = 16w..16w+15. Lane = dim.
    {
        int lane = tid & 63, w = tid >> 6;   // 8 waves x 16 m
#pragma unroll
        for (int t = 0; t < 16; ++t) {
            int m = (w << 4) | t;
            int bi = s_bi[m];
            float v = s_scr[m * 65 + lane];
            unsafeAtomicAdd(sumenc + ((size_t)bi << 6) + lane, v);
        }
    }
}

// 2048 blocks x 256 threads: csn (redundant per block, deterministic) +
// perplexity (block 0 only) + z_q + straight-through + loss + one-hot rows.
__global__ void __launch_bounds__(256) k_zq(const float* __restrict__ z,
                                            const int* __restrict__ idx,
                                            const float* __restrict__ ema_cs,
                                            const float* __restrict__ ema_w,
                                            const int* __restrict__ cnt,
                                            const float* __restrict__ sumenc,
                                            float* __restrict__ out) {
    __shared__ float s_csn[NE];
    __shared__ float swn[4], swe[4];
    __shared__ int sbi[16];
    int tid = threadIdx.x;
    bool doent = (blockIdx.x == 0);   // block-uniform: no divergence

    float myncs[4];
    float rn = 0.f, re = 0.f;
#pragma unroll
    for (int j = 0; j < 4; ++j) {
        int k = j * 256 + tid;
        float c = (float)cnt[k];
        float ncs = 0.99f * ema_cs[k] + (1.0f - 0.99f) * c;
        myncs[j] = ncs;
        rn += ncs;
        if (doent) {   // only block 0's entropy is ever consumed
            float p = c * (1.0f / (float)NVEC);
            re += p * logf(p + 1e-10f);
        }
    }
#pragma unroll
    for (int o = 32; o > 0; o >>= 1) {
        rn += __shfl_down(rn, o, 64);
        re += __shfl_down(re, o, 64);
    }
    int wave = tid >> 6;
    if ((tid & 63) == 0) { swn[wave] = rn; swe[wave] = re; }
    if (tid < 16) sbi[tid] = idx[blockIdx.x * 16 + tid];
    __syncthreads();
    float nt = (swn[0] + swn[1]) + (swn[2] + swn[3]);
    if (doent && tid == 0) {
        float te = (swe[0] + swe[1]) + (swe[2] + swe[3]);
        out[O_PERP] = expf(-te);
    }
#pragma unroll
    for (int j = 0; j < 4; ++j) {
        int k = j * 256 + tid;
        s_csn[k] = (myncs[j] + 1e-5f) / (nt + 1024.0f * 1e-5f) * nt;
    }
    __syncthreads();

    float local = 0.f;
#pragma unroll
    for (int i = 0; i < 4; ++i) {
        int t = blockIdx.x * 256 + tid + i * 524288;
        int b = t >> 16, c = (t >> 10) & 63, hw = t & 1023;
        int n = (b << 10) | hw;
        int g = idx[n] * ED + c;
        float nw = 0.99f * ema_w[g] + (1.0f - 0.99f) * sumenc[g];
        float e = nw / s_csn[g >> 6];
        float zv = z[t];
        float diff = e - zv;             // z_q - z
        out[O_ZQ + t] = zv + diff;       // straight-through: z + (z_q - z)
        local = fmaf(diff, diff, local);
    }

    // one-hot rows r0..r0+15
    int t = tid;
    int r0 = blockIdx.x * 16;
    for (int r = 0; r < 16; ++r) {
        int rbi = sbi[r];
        float* rp = out + O_MINENC + (size_t)(r0 + r) * NE;
        if (t < 254) {
            int col = 2 + t * 4;
            float4 v;
            v.x = (col == rbi) ? 1.0f : 0.0f;
            v.y = (col + 1 == rbi) ? 1.0f : 0.0f;
            v.z = (col + 2 == rbi) ? 1.0f : 0.0f;
            v.w = (col + 3 == rbi) ? 1.0f : 0.0f;
            *(float4*)(rp + col) = v;
        } else if (t == 254) {
            float2 v;
            v.x = (0 == rbi) ? 1.0f : 0.0f;
            v.y = (1 == rbi) ? 1.0f : 0.0f;
            *(float2*)(rp) = v;
        } else {
            float4 v;
            v.x = (1018 == rbi) ? 1.0f : 0.0f;
            v.y = (1019 == rbi) ? 1.0f : 0.0f;
            v.z = (1020 == rbi) ? 1.0f : 0.0f;
            v.w = (1021 == rbi) ? 1.0f : 0.0f;
            *(float4*)(rp + 1018) = v;
            float2 w;
            w.x = (1022 == rbi) ? 1.0f : 0.0f;
            w.y = (1023 == rbi) ? 1.0f : 0.0f;
            *(float2*)(rp + 1022) = w;
        }
    }

#pragma unroll
    for (int o = 32; o > 0; o >>= 1) local += __shfl_down(local, o, 64);
    __shared__ float sp[4];
    if ((tid & 63) == 0) sp[wave] = local;
    __syncthreads();
    if (tid == 0)
        unsafeAtomicAdd(out + O_LOSS,
                        ((sp[0] + sp[1]) + (sp[2] + sp[3])) * (0.25f / (float)TOT));
}

extern "C" void kernel_launch(void* const* d_in, const int* in_sizes, int n_in,
                              void* d_out, int out_size, void* d_ws, size_t ws_size,
                              hipStream_t stream) {
    const float* z      = (const float*)d_in[0];
    const float* emb    = (const float*)d_in[1];
    const float* ema_cs = (const float*)d_in[2];
    const float* ema_w  = (const float*)d_in[3];
    float* out = (float*)d_out;
    float* ws  = (float*)d_ws;

    k_pre<<<69, 256, 0, stream>>>(emb, ws, out);
    k_dist<<<NVEC / MT, 512, 0, stream>>>(z, emb, ws + W_ESQ, (int*)(ws + W_PIDX),
                                          (int*)(ws + W_CS), ws + W_SUMENC, out);
    k_zq<<<2048, 256, 0, stream>>>(z, (const int*)(ws + W_PIDX), ema_cs, ema_w,
                                   (const int*)(ws + W_CS), ws + W_SUMENC, out);
}

// Round 11
// 245.998 us; speedup vs baseline: 1.0193x; 1.0193x over previous
//
#include <hip/hip_runtime.h>
#include <math.h>

#define NVEC 32768   // 32*32*32 vectors
#define NE   1024    // codebook entries
#define ED   64      // embedding dim
#define TOT  2097152 // NVEC*ED total z elements
#define NCHUNK 4     // chunks per k-half (4 x 128 = 512 codes)
#define CHUNK  128   // codes per chunk
#define MT     128   // vectors per k_dist block

// d_out offsets (in floats): loss | z_q_st | perplexity | min_encodings | idx
#define O_LOSS   0
#define O_ZQ     1
#define O_PERP   2097153
#define O_MINENC 2097154
#define O_IDX    35651586

// d_ws offsets (in floats)
#define W_PIDX   0        // [32768] final idx (int), written by k_mrg
#define W_CS     32768    // [1024] int counts (atomic)
#define W_SUMENC 33792    // [1024*64] float (atomic)
#define W_ESQ    164864   // [1024] ||e||^2, exact np-pairwise

// R24 post-mortem of R23: global-B streaming REGRESSED (90->104): VMEM
// gather latency (~200cy) replaced LDS latency and still nothing hides it.
// Reverted. Signal from 7 variants: 2 INDEPENDENT blocks/CU runs at ~72%
// of the LDS-pipe bound (R2: 85us vs 61 bound), 1 block/CU at ~46%
// (R19-22: 90 vs 41) — independent blocks desync and hide each other's
// stalls; barrier-locked waves don't. R24 fills the missing matrix cell
// (1.0 B/FMA AND 2 blocks/CU): K SPLIT IN HALF. Block (tile, half) covers
// 512 codes; LDS = s_a 32K + s_b 33K = 66K -> 2 blocks/CU, grid 512.
// Per-half winner = lex (d,i) min (bit-identical d, same traversal) ->
// cross-half lex merge == np.argmin exactly (half0 idx < half1 idx).
// Candidates stashed in out[O_MINENC] (stream-ordered scratch, k_zq
// overwrites later). k_mrg: merge + idx outputs + cnt atomics + sumenc
// scatter via z gathers (z is L3-resident; 512 unique lines/block).

// blocks 0..64: zero cnt+sumenc (66560 floats = 16640 float4) + out[O_LOSS].
// blocks 65..68: esq[code] with the exact np-pairwise rounding.
__global__ void __launch_bounds__(256) k_pre(const float* __restrict__ emb,
                                             float* __restrict__ ws,
                                             float* __restrict__ out) {
    int b = blockIdx.x;
    if (b < 65) {
        int i = b * 256 + threadIdx.x;  // 0..16639, exactly 65*256
        float4 zv; zv.x = 0.f; zv.y = 0.f; zv.z = 0.f; zv.w = 0.f;
        *(float4*)(ws + W_CS + i * 4) = zv;
        if (b == 0 && threadIdx.x == 0) out[O_LOSS] = 0.f;
    } else {
        int code = (b - 65) * 256 + threadIdx.x;  // 4*256 = 1024
        const float* ep = emb + (size_t)code * ED;
        float r[8];
#pragma unroll
        for (int j = 0; j < 8; ++j) r[j] = __fmul_rn(ep[j], ep[j]);
#pragma unroll
        for (int i = 8; i < 64; i += 8)
#pragma unroll
            for (int j = 0; j < 8; ++j)
                r[j] = __fadd_rn(r[j], __fmul_rn(ep[i + j], ep[i + j]));
        ws[W_ESQ + code] = __fadd_rn(
            __fadd_rn(__fadd_rn(r[0], r[1]), __fadd_rn(r[2], r[3])),
            __fadd_rn(__fadd_rn(r[4], r[5]), __fadd_rn(r[6], r[7])));
    }
}

// phys float offset of logical m within an s_a row (perm'd quads)
__device__ __forceinline__ int apos(int m) {
    return ((m & 4) << 4) + ((m >> 3) << 2) + (m & 3);
}

// grid 512 = 256 m-tiles x 2 k-halves. 256 threads (4 waves). 8m x 8k tile.
__global__ void __launch_bounds__(256) k_dist(const float* __restrict__ z,
                                              const float* __restrict__ emb,
                                              const float* __restrict__ esq_g,
                                              float* __restrict__ out) {
    __shared__ __align__(16) float s_a[64 * 128];   // [c][m-perm] 2*z (32 KB)
    __shared__ __align__(16) float s_b[64 * 132];   // [c][k-swizzled] (33 KB)
    __shared__ float s_esq[CHUNK];
    __shared__ float s_zsq[MT];

    int tid = threadIdx.x;
    int tile = blockIdx.x >> 1, khalf = blockIdx.x & 1;
    int n0 = tile * MT;
    int b = n0 >> 10, hw0 = n0 & 1023;  // MT=128 tile never crosses b
    const float* zb = z + b * 65536 + hw0;

    // Stage A: 64c x 128m = 2048 float4 / 256 thr = 8 each. Perm'd quads.
#pragma unroll
    for (int j = 0; j < 8; ++j) {
        int f4i = j * 256 + tid;
        int q = f4i & 31, c = f4i >> 5;   // c in 0..63
        float4 v = *(const float4*)(zb + (c << 10) + q * 4);
        v.x = __fmul_rn(2.0f, v.x);
        v.y = __fmul_rn(2.0f, v.y);
        v.z = __fmul_rn(2.0f, v.z);
        v.w = __fmul_rn(2.0f, v.w);
        *(float4*)(s_a + c * 128 + ((q & 1) << 6) + ((q >> 1) << 2)) = v;
    }
    __syncthreads();

    // zsq (threads 0..127): np-pairwise over z; from (2z): exact x0.25.
    if (tid < MT) {
        int p = apos(tid);
        float r[8];
#pragma unroll
        for (int j = 0; j < 8; ++j) {
            float v = s_a[j * 128 + p];
            r[j] = __fmul_rn(v, v);
        }
#pragma unroll
        for (int i = 8; i < 64; i += 8)
#pragma unroll
            for (int j = 0; j < 8; ++j) {
                float v = s_a[(i + j) * 128 + p];
                r[j] = __fadd_rn(r[j], __fmul_rn(v, v));
            }
        s_zsq[tid] = __fmul_rn(0.25f, __fadd_rn(
            __fadd_rn(__fadd_rn(r[0], r[1]), __fadd_rn(r[2], r[3])),
            __fadd_rn(__fadd_rn(r[4], r[5]), __fadd_rn(r[6], r[7]))));
    }
    __syncthreads();

    int mi = tid & 15, ki = tid >> 4;   // 16 m-groups x 16 k-groups
    int kbase = ki * 8;                 // within chunk
    float zs[8];
#pragma unroll
    for (int mu = 0; mu < 8; ++mu) zs[mu] = s_zsq[8 * mi + mu];

    float bd[8];
    int bix[8];
#pragma unroll
    for (int mu = 0; mu < 8; ++mu) { bd[mu] = 3.4e38f; bix[mu] = khalf * 512 + kbase; }

    for (int ch = 0; ch < NCHUNK; ++ch) {
        int k0 = khalf * 512 + ch * CHUNK;   // global code base of chunk
        __syncthreads();  // previous chunk's readers of s_b/s_esq are done
        // Stage B: 128 codes x 16 f4 = 2048 f4 / 256 thr = 8 each. Proven
        // swizzle: phys quad (k4 + c4) & 31.
#pragma unroll
        for (int j = 0; j < 8; ++j) {
            int f4i = j * 256 + tid;
            int kl = f4i >> 4, c4 = f4i & 15;   // kl 0..127
            float4 v = *(const float4*)(emb + (size_t)(k0 + kl) * ED + c4 * 4);
            int base = (((kl >> 2) + c4) & 31) * 4 + (kl & 3);
            s_b[(c4 * 4 + 0) * 132 + base] = v.x;
            s_b[(c4 * 4 + 1) * 132 + base] = v.y;
            s_b[(c4 * 4 + 2) * 132 + base] = v.z;
            s_b[(c4 * 4 + 3) * 132 + base] = v.w;
        }
        if (tid < CHUNK) s_esq[tid] = esq_g[k0 + tid];
        __syncthreads();

        float acc[8][8];
#pragma unroll
        for (int mu = 0; mu < 8; ++mu)
#pragma unroll
            for (int ku = 0; ku < 8; ++ku) acc[mu][ku] = 0.f;

        // batch 4 c-iters of LDS loads, then 256 FMAs (c ascending order).
        for (int cg = 0; cg < 64; cg += 4) {
            float4 A0[4], A1[4], B0[4], B1[4];
#pragma unroll
            for (int j = 0; j < 4; ++j) {
                int c = cg + j;
                int c4 = c >> 2;
                const float* ar = s_a + c * 128 + (mi << 2);
                A0[j] = *(const float4*)(ar);        // m = 8mi..8mi+3
                A1[j] = *(const float4*)(ar + 64);   // m = 8mi+4..8mi+7
                B0[j] = *(const float4*)(s_b + c * 132 + ((2 * ki + c4) & 31) * 4);
                B1[j] = *(const float4*)(s_b + c * 132 + ((2 * ki + 1 + c4) & 31) * 4);
            }
#pragma unroll
            for (int j = 0; j < 4; ++j) {
#pragma unroll
                for (int mu = 0; mu < 8; ++mu) {
                    float a = (mu < 4) ? (&A0[j].x)[mu] : (&A1[j].x)[mu - 4];
                    acc[mu][0] = __fmaf_rn(a, B0[j].x, acc[mu][0]);
                    acc[mu][1] = __fmaf_rn(a, B0[j].y, acc[mu][1]);
                    acc[mu][2] = __fmaf_rn(a, B0[j].z, acc[mu][2]);
                    acc[mu][3] = __fmaf_rn(a, B0[j].w, acc[mu][3]);
                    acc[mu][4] = __fmaf_rn(a, B1[j].x, acc[mu][4]);
                    acc[mu][5] = __fmaf_rn(a, B1[j].y, acc[mu][5]);
                    acc[mu][6] = __fmaf_rn(a, B1[j].z, acc[mu][6]);
                    acc[mu][7] = __fmaf_rn(a, B1[j].w, acc[mu][7]);
                }
            }
        }

        // d = fl(fl(zsq+esq) - dot2); running per-thread argmin (k ascending)
#pragma unroll
        for (int mu = 0; mu < 8; ++mu)
#pragma unroll
            for (int ku = 0; ku < 8; ++ku) {
                float d = __fsub_rn(__fadd_rn(zs[mu], s_esq[kbase + ku]),
                                    acc[mu][ku]);
                if (d < bd[mu]) { bd[mu] = d; bix[mu] = k0 + kbase + ku; }
            }
    }

    // Merge 16 ki candidates per m (lex (d,i) min) -> per-half winner.
    __syncthreads();  // last chunk's readers of s_b done
    float* red_d = s_b;               // [16][128] = 2048 floats
    int* red_i = (int*)(s_b + 2048);  // [16][128]
#pragma unroll
    for (int mu = 0; mu < 8; ++mu) {
        red_d[ki * 128 + 8 * mi + mu] = bd[mu];
        red_i[ki * 128 + 8 * mi + mu] = bix[mu];
    }
    __syncthreads();
    if (tid < MT) {
        float best = red_d[tid];
        int bi = red_i[tid];
#pragma unroll
        for (int q = 1; q < 16; ++q) {
            float d = red_d[q * 128 + tid];
            int i = red_i[q * 128 + tid];
            if (d < best || (d == best && i < bi)) { best = d; bi = i; }
        }
        // stash candidate in out[O_MINENC] scratch (k_zq overwrites later)
        out[O_MINENC + khalf * 32768 + n0 + tid] = best;
        ((int*)(out + O_MINENC))[65536 + khalf * 32768 + n0 + tid] = bi;
    }
}

// 256 blocks x 256 thr: lex-merge the two half-candidates per m (== global
// np.argmin), write idx outputs + cnt atomics, then scatter z into sumenc
// (coalesced 256B atomics; z gathered from L3 — tile's lines are hot).
__global__ void __launch_bounds__(256) k_mrg(const float* __restrict__ z,
                                             int* __restrict__ fidx,
                                             int* __restrict__ cnt,
                                             float* __restrict__ sumenc,
                                             float* __restrict__ out) {
    __shared__ int s_bi[MT];
    int tid = threadIdx.x;
    int m0 = blockIdx.x * MT;   // 128 m per block

    if (tid < MT) {
        int m = m0 + tid;
        const float* cd = out + O_MINENC;
        const int* ci = (const int*)(out + O_MINENC) + 65536;
        float d0 = cd[m], d1 = cd[32768 + m];
        int i0 = ci[m], i1 = ci[32768 + m];
        // i0 < i1 always (half0 codes 0..511 < half1 512..1023): tie -> i0.
        int bi = (d1 < d0) ? i1 : i0;
        fidx[m] = bi;
        out[O_IDX + m] = (float)bi;
        s_bi[tid] = bi;
        atomicAdd(&cnt[bi], 1);
    }
    __syncthreads();

    // Scatter: wave w handles m-locals 32w..32w+31; lane = dim. Batch-4
    // independent gathers for MLP, then 4 coalesced 256B atomics.
    int lane = tid & 63, w = tid >> 6;
    int b = m0 >> 10, hw0 = m0 & 1023;   // block's m-range stays in one b
    const float* zc = z + b * 65536 + lane * 1024 + hw0;
#pragma unroll
    for (int t0 = 0; t0 < 32; t0 += 4) {
        float v[4];
#pragma unroll
        for (int u = 0; u < 4; ++u) {
            int ml = (w << 5) + t0 + u;
            v[u] = zc[ml];   // z[b][lane][hw0+ml]
        }
#pragma unroll
        for (int u = 0; u < 4; ++u) {
            int ml = (w << 5) + t0 + u;
            unsafeAtomicAdd(sumenc + ((size_t)s_bi[ml] << 6) + lane, v[u]);
        }
    }
}

// 2048 blocks x 256 threads: csn (redundant per block, deterministic) +
// perplexity (block 0 only) + z_q + straight-through + loss + one-hot rows.
__global__ void __launch_bounds__(256) k_zq(const float* __restrict__ z,
                                            const int* __restrict__ idx,
                                            const float* __restrict__ ema_cs,
                                            const float* __restrict__ ema_w,
                                            const int* __restrict__ cnt,
                                            const float* __restrict__ sumenc,
                                            float* __restrict__ out) {
    __shared__ float s_csn[NE];
    __shared__ float swn[4], swe[4];
    __shared__ int sbi[16];
    int tid = threadIdx.x;
    bool doent = (blockIdx.x == 0);   // block-uniform: no divergence

    float myncs[4];
    float rn = 0.f, re = 0.f;
#pragma unroll
    for (int j = 0; j < 4; ++j) {
        int k = j * 256 + tid;
        float c = (float)cnt[k];
        float ncs = 0.99f * ema_cs[k] + (1.0f - 0.99f) * c;
        myncs[j] = ncs;
        rn += ncs;
        if (doent) {   // only block 0's entropy is ever consumed
            float p = c * (1.0f / (float)NVEC);
            re += p * logf(p + 1e-10f);
        }
    }
#pragma unroll
    for (int o = 32; o > 0; o >>= 1) {
        rn += __shfl_down(rn, o, 64);
        re += __shfl_down(re, o, 64);
    }
    int wave = tid >> 6;
    if ((tid & 63) == 0) { swn[wave] = rn; swe[wave] = re; }
    if (tid < 16) sbi[tid] = idx[blockIdx.x * 16 + tid];
    __syncthreads();
    float nt = (swn[0] + swn[1]) + (swn[2] + swn[3]);
    if (doent && tid == 0) {
        float te = (swe[0] + swe[1]) + (swe[2] + swe[3]);
        out[O_PERP] = expf(-te);
    }
#pragma unroll
    for (int j = 0; j < 4; ++j) {
        int k = j * 256 + tid;
        s_csn[k] = (myncs[j] + 1e-5f) / (nt + 1024.0f * 1e-5f) * nt;
    }
    __syncthreads();

    float local = 0.f;
#pragma unroll
    for (int i = 0; i < 4; ++i) {
        int t = blockIdx.x * 256 + tid + i * 524288;
        int b = t >> 16, c = (t >> 10) & 63, hw = t & 1023;
        int n = (b << 10) | hw;
        int g = idx[n] * ED + c;
        float nw = 0.99f * ema_w[g] + (1.0f - 0.99f) * sumenc[g];
        float e = nw / s_csn[g >> 6];
        float zv = z[t];
        float diff = e - zv;             // z_q - z
        out[O_ZQ + t] = zv + diff;       // straight-through: z + (z_q - z)
        local = fmaf(diff, diff, local);
    }

    // one-hot rows r0..r0+15
    int t = tid;
    int r0 = blockIdx.x * 16;
    for (int r = 0; r < 16; ++r) {
        int rbi = sbi[r];
        float* rp = out + O_MINENC + (size_t)(r0 + r) * NE;
        if (t < 254) {
            int col = 2 + t * 4;
            float4 v;
            v.x = (col == rbi) ? 1.0f : 0.0f;
            v.y = (col + 1 == rbi) ? 1.0f : 0.0f;
            v.z = (col + 2 == rbi) ? 1.0f : 0.0f;
            v.w = (col + 3 == rbi) ? 1.0f : 0.0f;
            *(float4*)(rp + col) = v;
        } else if (t == 254) {
            float2 v;
            v.x = (0 == rbi) ? 1.0f : 0.0f;
            v.y = (1 == rbi) ? 1.0f : 0.0f;
            *(float2*)(rp) = v;
        } else {
            float4 v;
            v.x = (1018 == rbi) ? 1.0f : 0.0f;
            v.y = (1019 == rbi) ? 1.0f : 0.0f;
            v.z = (1020 == rbi) ? 1.0f : 0.0f;
            v.w = (1021 == rbi) ? 1.0f : 0.0f;
            *(float4*)(rp + 1018) = v;
            float2 w;
            w.x = (1022 == rbi) ? 1.0f : 0.0f;
            w.y = (1023 == rbi) ? 1.0f : 0.0f;
            *(float2*)(rp + 1022) = w;
        }
    }

#pragma unroll
    for (int o = 32; o > 0; o >>= 1) local += __shfl_down(local, o, 64);
    __shared__ float sp[4];
    if ((tid & 63) == 0) sp[wave] = local;
    __syncthreads();
    if (tid == 0)
        unsafeAtomicAdd(out + O_LOSS,
                        ((sp[0] + sp[1]) + (sp[2] + sp[3])) * (0.25f / (float)TOT));
}

extern "C" void kernel_launch(void* const* d_in, const int* in_sizes, int n_in,
                              void* d_out, int out_size, void* d_ws, size_t ws_size,
                              hipStream_t stream) {
    const float* z      = (const float*)d_in[0];
    const float* emb    = (const float*)d_in[1];
    const float* ema_cs = (const float*)d_in[2];
    const float* ema_w  = (const float*)d_in[3];
    float* out = (float*)d_out;
    float* ws  = (float*)d_ws;

    k_pre<<<69, 256, 0, stream>>>(emb, ws, out);
    k_dist<<<512, 256, 0, stream>>>(z, emb, ws + W_ESQ, out);
    k_mrg<<<256, 256, 0, stream>>>(z, (int*)(ws + W_PIDX), (int*)(ws + W_CS),
                                   ws + W_SUMENC, out);
    k_zq<<<2048, 256, 0, stream>>>(z, (const int*)(ws + W_PIDX), ema_cs, ema_w,
                                   (const int*)(ws + W_CS), ws + W_SUMENC, out);
}